// Round 5
// baseline (141.332 us; speedup 1.0000x reference)
//
#include <hip/hip_runtime.h>
#include <hip/hip_bf16.h>

// B=8, T=1024, D=128, TEMP=0.1, WEIGHT=1.0. 56 ordered pairs (i,j), i!=j.
// All-fp8 (OCP e4m3) datapath:
//   Q,K stored *SQDS; z = dot(q',k') = 2qk*log2e/12.8
//   p' = exp2(z - 6), bias in MFMA C-init, CLAMPED to 448 (R12 NaN fix)
//   V'' = g14*SQDS*e2, g14 = exp2(14 - |e|^2*NSCALE), elements CLAMPED +-440
//   L, sum(p*g*sp) via 5th V-block rows [g14; g14*sp] -> all-fp8 PV
//   Bias/2^14 factors cancel in nn = O/L and pred = tp/L2.
// R17: independent single-wave workgroups + private LDS staging.
// Evidence: R12=R14=R16=62us (barrier-locked waves: MFMA/VALU never co-issue,
// MfmaUtil+VALUBusy pinned ~63%; intra-wave reordering null per m253);
// R15=78us (independent waves but direct-L2 operands: latency exposure).
// The unexplored quadrant: independent waves WITH LDS operands. Each 64-thread
// block = 1 wave, stages its own s-32 K/V tile via global_load_lds into a
// private 2x9216B double buffer. ZERO barriers; counted per-wave vmcnt(9/5)
// waits for loads issued one full compute interval earlier. Grid 56*32=1792
// (7/CU, LDS allows 8/CU) -> de-phased waves co-fill MFMA+VALU pipes (m114).
// Per-wave 32-s compute math identical to refcheck-passed R13 variant.

#define T_ 1024
#define D_ 128
#define NPAIR 56
#define NSCALE 0.11271055006945026f   // (1/12.8)*log2(e)
#define SQDS 0.474785316f             // sqrt((2/12.8)*log2(e))

typedef float f32x16 __attribute__((ext_vector_type(16)));

#define B8F 131072   // bytes per batch: Q/K frags (256 chunks * 512B)
#define B8T 163840   // bytes per batch: V'' frags (320 chunks: 4 d-blocks + g-block)

__device__ __forceinline__ unsigned short f2bf(float f) {
  unsigned u = __float_as_uint(f);
  u += 0x7fff + ((u >> 16) & 1);
  return (unsigned short)(u >> 16);
}
__device__ __forceinline__ float bf2f(unsigned short v) {
  return __uint_as_float(((unsigned)v) << 16);
}
__device__ __forceinline__ float clamp8(float x) {
  return fminf(fmaxf(x, -440.f), 440.f);
}
__device__ __forceinline__ unsigned pk4(float a, float b, float c, float d) {
  int w = __builtin_amdgcn_cvt_pk_fp8_f32(a, b, 0, false);
  w = __builtin_amdgcn_cvt_pk_fp8_f32(c, d, w, true);
  return (unsigned)w;
}
__device__ __forceinline__ float waveSum(float v) {
#pragma unroll
  for (int k = 32; k >= 1; k >>= 1) v += __shfl_xor(v, k, 64);
  return v;
}
__device__ __forceinline__ void stage1k(const unsigned char* g, unsigned char* lds, int lane) {
  __builtin_amdgcn_global_load_lds(
      (const __attribute__((address_space(1))) unsigned int*)(g + lane * 16),
      (__attribute__((address_space(3))) unsigned int*)lds, 16, 0, 0);
}

// fp8 C->B transform. m[0..3] = pk4 of C-regs rg 0-3 / 4-7 / 8-11 / 12-15
// (rows 4lh+0..3, 8+4lh+.., 16+.., 24+..). Output: two 16-k B chunks (8 fp8 = i64).
__device__ __forceinline__ void c2b8(const unsigned* m, int lh, long long* b0, long long* b1) {
  unsigned send0 = lh ? m[0] : m[1];
  unsigned send1 = lh ? m[2] : m[3];
  unsigned r0 = (unsigned)__shfl_xor((int)send0, 32, 64);
  unsigned r1 = (unsigned)__shfl_xor((int)send1, 32, 64);
  union { unsigned u[2]; long long ll; } x0, x1;
  x0.u[0] = lh ? r0 : m[0];  x0.u[1] = lh ? m[1] : r0;
  x1.u[0] = lh ? r1 : m[2];  x1.u[1] = lh ? m[3] : r1;
  *b0 = x0.ll; *b1 = x1.ll;
}

#define MFMA8(A, B, C) __builtin_amdgcn_mfma_f32_32x32x16_fp8_fp8((A), (B), (C), 0, 0, 0)
#define LD8(P, Q) (*(const long long*)((P) + (Q) * 512))
#define EXPC(x) fminf(__builtin_amdgcn_exp2f(x), 448.f)
#define WAITV(N) asm volatile("s_waitcnt vmcnt(" #N ")" ::: "memory")
#define WAITL() asm volatile("s_waitcnt lgkmcnt(0)" ::: "memory")

// ---- convert: fp32 -> fp8 frag buffers + steps + ws init ----
__global__ __launch_bounds__(256) void convert_kernel(
    const float* __restrict__ embs, const int* __restrict__ fi,
    const int* __restrict__ vl, unsigned char* __restrict__ e8F,
    unsigned char* __restrict__ e8T, float* __restrict__ steps,
    float* __restrict__ acc, unsigned* __restrict__ cnt) {
  __shared__ unsigned short tileS[32 * 136];
  __shared__ float psum[32][8];
  __shared__ float g_sh[32], sp_sh[32];
  const int b = blockIdx.x >> 5;
  const int t0 = (blockIdx.x & 31) * 32;
  const int tid = threadIdx.x;
  const int row = tid >> 3, seg = tid & 7;

  if (blockIdx.x == 0 && tid == 0) { acc[0] = 0.f; cnt[0] = 0u; }

  const float* src = embs + (size_t)(b * T_ + t0 + row) * D_ + seg * 16;
  float4 g4[4];
#pragma unroll
  for (int k = 0; k < 4; k++) g4[k] = ((const float4*)src)[k];
  float s = 0.f;
  float fv[16];
#pragma unroll
  for (int k = 0; k < 4; k++) {
    s += g4[k].x * g4[k].x + g4[k].y * g4[k].y + g4[k].z * g4[k].z + g4[k].w * g4[k].w;
    fv[4 * k + 0] = g4[k].x * SQDS; fv[4 * k + 1] = g4[k].y * SQDS;
    fv[4 * k + 2] = g4[k].z * SQDS; fv[4 * k + 3] = g4[k].w * SQDS;
  }
  psum[row][seg] = s;

  // e8F store: chunk (t>>5)*8 + seg; lanes row (d lo 8) and 32+row (d hi 8)
  {
    unsigned char* dstA = e8F + (size_t)b * B8F + (size_t)((t0 >> 5) * 8 + seg) * 512;
    uint2 lo, hi;
    lo.x = pk4(fv[0], fv[1], fv[2], fv[3]);   lo.y = pk4(fv[4], fv[5], fv[6], fv[7]);
    hi.x = pk4(fv[8], fv[9], fv[10], fv[11]); hi.y = pk4(fv[12], fv[13], fv[14], fv[15]);
    *(uint2*)(dstA + row * 8) = lo;
    *(uint2*)(dstA + (size_t)(32 + row) * 8) = hi;
  }
  // bf16 tile for the transpose
#pragma unroll
  for (int k = 0; k < 16; k++) tileS[row * 136 + seg * 16 + k] = f2bf(fv[k]);
  __syncthreads();

  if (tid < 32) {
    float t = 0.f;
#pragma unroll
    for (int k = 0; k < 8; k++) t += psum[tid][k];
    int gr = b * T_ + t0 + tid;
    float sp = (float)fi[gr] / (float)vl[b];
    steps[gr] = sp;
    sp_sh[tid] = sp;
    g_sh[tid] = __builtin_amdgcn_exp2f(14.0f - t * NSCALE);   // g14
  }
  __syncthreads();

  // e8T d-blocks 0..3: V'' = g14 * (SQDS*e), transposed, clamped to fp8 range
  {
    const int c8 = tid >> 5;
    const int n2 = c8 & 3, scp = c8 >> 2;
    const int dd = n2 * 32 + (tid & 31);
#pragma unroll
    for (int half = 0; half < 2; half++) {
      const int lane = half * 32 + (tid & 31);
      const int sl = scp * 16 + half * 8;
      float vv[8];
#pragma unroll
      for (int jj = 0; jj < 8; jj++)
        vv[jj] = clamp8(bf2f(tileS[(sl + jj) * 136 + dd]) * g_sh[sl + jj]);
      uint2 wv;
      wv.x = pk4(vv[0], vv[1], vv[2], vv[3]);
      wv.y = pk4(vv[4], vv[5], vv[6], vv[7]);
      int c = n2 * 64 + (t0 >> 4) + scp;
      *(uint2*)(e8T + (size_t)b * B8T + (size_t)c * 512 + lane * 8) = wv;
    }
  }
  // e8T g-block (n2=4): row m=0 -> g14, m=1 -> g14*sp, else 0 (clamped)
  if (tid < 128) {
    const int sc2 = tid >> 6, lane = tid & 63;
    const int m = lane & 31, kh = lane >> 5;
    uint2 wv; wv.x = 0u; wv.y = 0u;
    if (m < 2) {
      float vv[8];
#pragma unroll
      for (int e = 0; e < 8; e++) {
        int sl = sc2 * 16 + kh * 8 + e;
        float gg = g_sh[sl];
        vv[e] = clamp8(m ? gg * sp_sh[sl] : gg);
      }
      wv.x = pk4(vv[0], vv[1], vv[2], vv[3]);
      wv.y = pk4(vv[4], vv[5], vv[6], vv[7]);
    }
    int c = 256 + (t0 >> 4) + sc2;
    *(uint2*)(e8T + (size_t)b * B8T + (size_t)c * 512 + lane * 8) = wv;
  }
}

__global__ __launch_bounds__(64) void tcc_main(
    const unsigned char* __restrict__ e8F, const unsigned char* __restrict__ e8T,
    const float* __restrict__ steps, float* __restrict__ loss_acc,
    unsigned* __restrict__ cnt, float* __restrict__ out) {
  // Single wave per block. Private double buffer: per s-32 tile
  //   phase 1: K 4096 B + V(4 d-blocks + g) 5120 B = 9216 B
  //   phase 2: K 4096 B + g 1024 B (same 9216 stride)
  __shared__ unsigned char smem[18432];

  const int bx = blockIdx.x;
  const int pair = bx >> 5;
  const int tile = bx & 31;
  const int i = pair / 7;
  const int r = pair % 7;
  const int j = r + (r >= i ? 1 : 0);
  const int l = threadIdx.x & 63;
  const int l31 = l & 31;
  const int lh = l >> 5;
  const int tb = tile * 32;

  const unsigned char* eFi = e8F + (size_t)i * B8F;
  const unsigned char* eFj = e8F + (size_t)j * B8F;
  const unsigned char* eTj = e8T + (size_t)j * B8T;
  const unsigned char* eTi = e8T + (size_t)i * B8T;

  // Q fp8 B-operand chunks (n=t, k=d) for this wave's 32 rows
  long long qf8[8];
  {
    const unsigned char* qb = eFi + (size_t)(tile * 8) * 512 + l * 8;
#pragma unroll
    for (int kc = 0; kc < 8; kc++) qf8[kc] = LD8(qb, kc);
  }

  const f32x16 Z = {0.f, 0.f, 0.f, 0.f, 0.f, 0.f, 0.f, 0.f,
                    0.f, 0.f, 0.f, 0.f, 0.f, 0.f, 0.f, 0.f};
  const f32x16 CM6 = {-6.f, -6.f, -6.f, -6.f, -6.f, -6.f, -6.f, -6.f,
                      -6.f, -6.f, -6.f, -6.f, -6.f, -6.f, -6.f, -6.f};
  f32x16 o[5];   // o[0..3]=O^T d-blocks, o[4]=g-block (row0=L')
#pragma unroll
  for (int n2 = 0; n2 < 5; n2++) o[n2] = Z;

  // stage phase-1 s-32 tile t into buffer b: 9 x 1KB units (4 K + 4 V + 1 g)
  auto stg1 = [&](int t, int b) {
    unsigned char* dst = smem + b * 9216;
#pragma unroll
    for (int u = 0; u < 4; u++)
      stage1k(eFj + ((size_t)t * 8 + u * 2) * 512, dst + u * 1024, l);
#pragma unroll
    for (int n2 = 0; n2 < 4; n2++)
      stage1k(eTj + ((size_t)n2 * 64 + t * 2) * 512, dst + 4096 + n2 * 1024, l);
    stage1k(eTj + ((size_t)256 + t * 2) * 512, dst + 4096 + 4096, l);
  };
  // stage phase-2 s-32 tile t into buffer b: 5 x 1KB units (4 K + 1 g)
  auto stg2 = [&](int t, int b) {
    unsigned char* dst = smem + b * 9216;
#pragma unroll
    for (int u = 0; u < 4; u++)
      stage1k(eFi + ((size_t)t * 8 + u * 2) * 512, dst + u * 1024, l);
    stage1k(eTi + ((size_t)256 + t * 2) * 512, dst + 4096, l);
  };

  // ---------------- phase 1: s-tile 32, 32 iterations, zero barriers ----------------
  stg1(0, 0);
  stg1(1, 1);

  for (int st = 0; st < 32; st++) {
    const int buf = st & 1;
    // wait for tile st (issued >= one full compute interval ago); keep st+1 in flight
    if (st == 31) { WAITV(0); } else { WAITV(9); }

    const unsigned char* kb = smem + buf * 9216 + l * 8;
    const unsigned char* vb = kb + 4096;

    // QK: one 8-deep chain (C-init = -6 bias)
    f32x16 ca = MFMA8(LD8(kb, 0), qf8[0], CM6);
#pragma unroll
    for (int dc = 1; dc < 8; dc++) ca = MFMA8(LD8(kb, dc), qf8[dc], ca);
    unsigned m0[4];
#pragma unroll
    for (int k2 = 0; k2 < 4; k2++)
      m0[k2] = pk4(EXPC(ca[4 * k2]), EXPC(ca[4 * k2 + 1]),
                   EXPC(ca[4 * k2 + 2]), EXPC(ca[4 * k2 + 3]));
    long long pB[2];
    c2b8(m0, lh, &pB[0], &pB[1]);
#pragma unroll
    for (int n2 = 0; n2 < 5; n2++)
#pragma unroll
      for (int sc = 0; sc < 2; sc++)
        o[n2] = MFMA8(LD8(vb, n2 * 2 + sc), pB[sc], o[n2]);

    if (st < 30) {
      WAITL();             // this buffer's ds_reads retired before overwrite
      stg1(st + 2, buf);
    }
  }

  // stage phase-2 tiles 0,1 (loads fly under the interphase register math)
  WAITL();
  stg2(0, 0);
  stg2(1, 1);

  // ---- interphase: nn^T = O^T / L'; fp8 B-frags via shfl (registers only) ----
  float Lme = o[4][0];
  float Lo = __shfl_xor(Lme, 32, 64);
  float inv = 1.0f / (lh ? Lo : Lme);
  long long qf2[8];
#pragma unroll
  for (int n2 = 0; n2 < 4; n2++) {
    unsigned mm[4];
#pragma unroll
    for (int k2 = 0; k2 < 4; k2++)
      mm[k2] = pk4(o[n2][4 * k2] * inv, o[n2][4 * k2 + 1] * inv,
                   o[n2][4 * k2 + 2] * inv, o[n2][4 * k2 + 3] * inv);
    c2b8(mm, lh, &qf2[2 * n2], &qf2[2 * n2 + 1]);
  }
  f32x16 acc6 = Z;

  // ---------------- phase 2: s-tile 32, 32 iterations, K + g-block ----------------
  for (int st = 0; st < 32; st++) {
    const int buf = st & 1;
    if (st == 31) { WAITV(0); } else { WAITV(5); }

    const unsigned char* kb = smem + buf * 9216 + l * 8;
    const unsigned char* gb = kb + 4096;

    f32x16 da = MFMA8(LD8(kb, 0), qf2[0], CM6);
#pragma unroll
    for (int dc = 1; dc < 8; dc++) da = MFMA8(LD8(kb, dc), qf2[dc], da);
    unsigned m0[4];
#pragma unroll
    for (int k2 = 0; k2 < 4; k2++)
      m0[k2] = pk4(EXPC(da[4 * k2]), EXPC(da[4 * k2 + 1]),
                   EXPC(da[4 * k2 + 2]), EXPC(da[4 * k2 + 3]));
    long long pB[2];
    c2b8(m0, lh, &pB[0], &pB[1]);
#pragma unroll
    for (int sc = 0; sc < 2; sc++)
      acc6 = MFMA8(LD8(gb, sc), pB[sc], acc6);

    if (st < 30) {
      WAITL();
      stg2(st + 2, buf);
    }
  }

  // ---- epilogue: pred = tp/L2 (rows 0,1 at lh=0), MSE, fused finalize ----
  float local = 0.f;
  if (lh == 0) {
    float pred = acc6[1] / acc6[0];
    float tt = steps[i * T_ + tb + l31];
    float dd = pred - tt;
    local = dd * dd;
  }
  local = waveSum(local);
  if (l == 0) {
    atomicAdd(loss_acc, local);
    __threadfence();
    unsigned old = atomicAdd(cnt, 1u);
    if (old == (unsigned)(gridDim.x - 1)) {
      float v = atomicAdd(loss_acc, 0.0f);
      out[0] = v * (1.0f / (float)(NPAIR * T_));
    }
  }
}

extern "C" void kernel_launch(void* const* d_in, const int* in_sizes, int n_in,
                              void* d_out, int out_size, void* d_ws, size_t ws_size,
                              hipStream_t stream) {
  const float* embs = (const float*)d_in[0];
  const int* frame_idxs = (const int*)d_in[1];
  const int* video_len = (const int*)d_in[2];
  float* out = (float*)d_out;

  char* ws = (char*)d_ws;
  float* acc = (float*)ws;                                  // @0
  unsigned* cnt = (unsigned*)(ws + 512);                    // @512
  float* steps = (float*)(ws + 4096);                       // 8192 f32
  unsigned char* e8F = (unsigned char*)(ws + 65536);        // 1 MB
  unsigned char* e8T = e8F + (size_t)8 * B8F;               // 1.25 MB

  convert_kernel<<<dim3(256), dim3(256), 0, stream>>>(embs, frame_idxs, video_len,
                                                      e8F, e8T, steps, acc, cnt);
  tcc_main<<<dim3(NPAIR * 32), dim3(64), 0, stream>>>(e8F, e8T, steps, acc, cnt, out);
}

// Round 6
// 122.792 us; speedup vs baseline: 1.1510x; 1.1510x over previous
//
#include <hip/hip_runtime.h>
#include <hip/hip_bf16.h>

// B=8, T=1024, D=128, TEMP=0.1, WEIGHT=1.0. 56 ordered pairs (i,j), i!=j.
// All-fp8 (OCP e4m3) datapath:
//   Q,K stored *SQDS; z = dot(q',k') = 2qk*log2e/12.8
//   p' = exp2(z - 6), bias in MFMA C-init, CLAMPED to 448 (R12 NaN fix)
//   V'' = g14*SQDS*e2, g14 = exp2(14 - |e|^2*NSCALE), elements CLAMPED +-440
//   L, sum(p*g*sp) via 5th V-block rows [g14; g14*sp] -> all-fp8 PV
//   Bias/2^14 factors cancel in nn = O/L and pred = tp/L2.
// R18: 2-wave blocks for cross-block de-phasing. Evidence: R12=R14=R16=62us
// (4-wave lockstep convoys; 448 blocks = 1.75/CU -> 64 CUs have ONE convoy,
// zero de-phasing partners; MfmaUtil+VALUBusy pinned ~63%); R13/R15/R17
// regressed whenever per-wave ILP or shared staging was sacrificed.
// Fix: keep R12's per-wave inner loop EXACTLY (2x8 QK chains, 5 PV chains,
// dbuf + syncthreads skeleton); decompose as 896 blocks x 128 threads
// (2 waves, 64 q-rows). LDS 36.9KB (gt overlays dead vt in phase 2) ->
// 4 blocks/CU -> 3-4 independent convoys per CU; one block's MFMA phase
// overlaps another's exp2/convert phase (m114). setprio(1) around MFMA
// clusters (T5 pays when co-resident waves are at different phases, m224).

#define T_ 1024
#define D_ 128
#define NPAIR 56
#define NSCALE 0.11271055006945026f   // (1/12.8)*log2(e)
#define SQDS 0.474785316f             // sqrt((2/12.8)*log2(e))

typedef float f32x16 __attribute__((ext_vector_type(16)));

#define B8F 131072   // bytes per batch: Q/K frags (256 chunks * 512B)
#define B8T 163840   // bytes per batch: V'' frags (320 chunks: 4 d-blocks + g-block)

__device__ __forceinline__ unsigned short f2bf(float f) {
  unsigned u = __float_as_uint(f);
  u += 0x7fff + ((u >> 16) & 1);
  return (unsigned short)(u >> 16);
}
__device__ __forceinline__ float bf2f(unsigned short v) {
  return __uint_as_float(((unsigned)v) << 16);
}
__device__ __forceinline__ float clamp8(float x) {
  return fminf(fmaxf(x, -440.f), 440.f);
}
__device__ __forceinline__ unsigned pk4(float a, float b, float c, float d) {
  int w = __builtin_amdgcn_cvt_pk_fp8_f32(a, b, 0, false);
  w = __builtin_amdgcn_cvt_pk_fp8_f32(c, d, w, true);
  return (unsigned)w;
}
__device__ __forceinline__ float waveSum(float v) {
#pragma unroll
  for (int k = 32; k >= 1; k >>= 1) v += __shfl_xor(v, k, 64);
  return v;
}
__device__ __forceinline__ void stage1k(const unsigned char* g, unsigned char* lds, int lane) {
  __builtin_amdgcn_global_load_lds(
      (const __attribute__((address_space(1))) unsigned int*)(g + lane * 16),
      (__attribute__((address_space(3))) unsigned int*)lds, 16, 0, 0);
}

// fp8 C->B transform. m[0..3] = pk4 of C-regs rg 0-3 / 4-7 / 8-11 / 12-15
// (rows 4lh+0..3, 8+4lh+.., 16+.., 24+..). Output: two 16-k B chunks (8 fp8 = i64).
__device__ __forceinline__ void c2b8(const unsigned* m, int lh, long long* b0, long long* b1) {
  unsigned send0 = lh ? m[0] : m[1];
  unsigned send1 = lh ? m[2] : m[3];
  unsigned r0 = (unsigned)__shfl_xor((int)send0, 32, 64);
  unsigned r1 = (unsigned)__shfl_xor((int)send1, 32, 64);
  union { unsigned u[2]; long long ll; } x0, x1;
  x0.u[0] = lh ? r0 : m[0];  x0.u[1] = lh ? m[1] : r0;
  x1.u[0] = lh ? r1 : m[2];  x1.u[1] = lh ? m[3] : r1;
  *b0 = x0.ll; *b1 = x1.ll;
}

#define MFMA8(A, B, C) __builtin_amdgcn_mfma_f32_32x32x16_fp8_fp8((A), (B), (C), 0, 0, 0)
#define LD8(P, Q) (*(const long long*)((P) + (Q) * 512))
#define EXPC(x) fminf(__builtin_amdgcn_exp2f(x), 448.f)

// ---- convert: fp32 -> fp8 frag buffers + steps + ws init ----
__global__ __launch_bounds__(256) void convert_kernel(
    const float* __restrict__ embs, const int* __restrict__ fi,
    const int* __restrict__ vl, unsigned char* __restrict__ e8F,
    unsigned char* __restrict__ e8T, float* __restrict__ steps,
    float* __restrict__ acc, unsigned* __restrict__ cnt) {
  __shared__ unsigned short tileS[32 * 136];
  __shared__ float psum[32][8];
  __shared__ float g_sh[32], sp_sh[32];
  const int b = blockIdx.x >> 5;
  const int t0 = (blockIdx.x & 31) * 32;
  const int tid = threadIdx.x;
  const int row = tid >> 3, seg = tid & 7;

  if (blockIdx.x == 0 && tid == 0) { acc[0] = 0.f; cnt[0] = 0u; }

  const float* src = embs + (size_t)(b * T_ + t0 + row) * D_ + seg * 16;
  float4 g4[4];
#pragma unroll
  for (int k = 0; k < 4; k++) g4[k] = ((const float4*)src)[k];
  float s = 0.f;
  float fv[16];
#pragma unroll
  for (int k = 0; k < 4; k++) {
    s += g4[k].x * g4[k].x + g4[k].y * g4[k].y + g4[k].z * g4[k].z + g4[k].w * g4[k].w;
    fv[4 * k + 0] = g4[k].x * SQDS; fv[4 * k + 1] = g4[k].y * SQDS;
    fv[4 * k + 2] = g4[k].z * SQDS; fv[4 * k + 3] = g4[k].w * SQDS;
  }
  psum[row][seg] = s;

  // e8F store: chunk (t>>5)*8 + seg; lanes row (d lo 8) and 32+row (d hi 8)
  {
    unsigned char* dstA = e8F + (size_t)b * B8F + (size_t)((t0 >> 5) * 8 + seg) * 512;
    uint2 lo, hi;
    lo.x = pk4(fv[0], fv[1], fv[2], fv[3]);   lo.y = pk4(fv[4], fv[5], fv[6], fv[7]);
    hi.x = pk4(fv[8], fv[9], fv[10], fv[11]); hi.y = pk4(fv[12], fv[13], fv[14], fv[15]);
    *(uint2*)(dstA + row * 8) = lo;
    *(uint2*)(dstA + (size_t)(32 + row) * 8) = hi;
  }
  // bf16 tile for the transpose
#pragma unroll
  for (int k = 0; k < 16; k++) tileS[row * 136 + seg * 16 + k] = f2bf(fv[k]);
  __syncthreads();

  if (tid < 32) {
    float t = 0.f;
#pragma unroll
    for (int k = 0; k < 8; k++) t += psum[tid][k];
    int gr = b * T_ + t0 + tid;
    float sp = (float)fi[gr] / (float)vl[b];
    steps[gr] = sp;
    sp_sh[tid] = sp;
    g_sh[tid] = __builtin_amdgcn_exp2f(14.0f - t * NSCALE);   // g14
  }
  __syncthreads();

  // e8T d-blocks 0..3: V'' = g14 * (SQDS*e), transposed, clamped to fp8 range
  {
    const int c8 = tid >> 5;
    const int n2 = c8 & 3, scp = c8 >> 2;
    const int dd = n2 * 32 + (tid & 31);
#pragma unroll
    for (int half = 0; half < 2; half++) {
      const int lane = half * 32 + (tid & 31);
      const int sl = scp * 16 + half * 8;
      float vv[8];
#pragma unroll
      for (int jj = 0; jj < 8; jj++)
        vv[jj] = clamp8(bf2f(tileS[(sl + jj) * 136 + dd]) * g_sh[sl + jj]);
      uint2 wv;
      wv.x = pk4(vv[0], vv[1], vv[2], vv[3]);
      wv.y = pk4(vv[4], vv[5], vv[6], vv[7]);
      int c = n2 * 64 + (t0 >> 4) + scp;
      *(uint2*)(e8T + (size_t)b * B8T + (size_t)c * 512 + lane * 8) = wv;
    }
  }
  // e8T g-block (n2=4): row m=0 -> g14, m=1 -> g14*sp, else 0 (clamped)
  if (tid < 128) {
    const int sc2 = tid >> 6, lane = tid & 63;
    const int m = lane & 31, kh = lane >> 5;
    uint2 wv; wv.x = 0u; wv.y = 0u;
    if (m < 2) {
      float vv[8];
#pragma unroll
      for (int e = 0; e < 8; e++) {
        int sl = sc2 * 16 + kh * 8 + e;
        float gg = g_sh[sl];
        vv[e] = clamp8(m ? gg * sp_sh[sl] : gg);
      }
      wv.x = pk4(vv[0], vv[1], vv[2], vv[3]);
      wv.y = pk4(vv[4], vv[5], vv[6], vv[7]);
    }
    int c = 256 + (t0 >> 4) + sc2;
    *(uint2*)(e8T + (size_t)b * B8T + (size_t)c * 512 + lane * 8) = wv;
  }
}

__global__ __launch_bounds__(128, 2) void tcc_main(
    const unsigned char* __restrict__ e8F, const unsigned char* __restrict__ e8T,
    const float* __restrict__ steps, float* __restrict__ loss_acc,
    unsigned* __restrict__ cnt, float* __restrict__ out) {
  // kt 2x8192 | vt 2x10240 = 36864 B; phase 2's gt (2x2048) overlays vt.
  // 36.9 KB -> 4 blocks/CU (160 KB LDS).
  __shared__ unsigned char smem[36864];
  __shared__ float blred[2];
  unsigned char* kt = smem;
  unsigned char* vt = smem + 16384;
  unsigned char* gt = smem + 16384;   // overlay: vt dead in phase 2

  const int bx = blockIdx.x;
  const int pair = bx >> 4;
  const int tile = bx & 15;
  const int i = pair / 7;
  const int r = pair % 7;
  const int j = r + (r >= i ? 1 : 0);
  const int tid = threadIdx.x;
  const int w = tid >> 6;          // 2 waves per block
  const int l = tid & 63;
  const int l31 = l & 31;
  const int lh = l >> 5;
  const int tb = tile * 64 + w * 32;

  const unsigned char* eFi = e8F + (size_t)i * B8F;
  const unsigned char* eFj = e8F + (size_t)j * B8F;
  const unsigned char* eTj = e8T + (size_t)j * B8T;
  const unsigned char* eTi = e8T + (size_t)i * B8T;

  // Q fp8 B-operand chunks (n=t, k=d)
  long long qf8[8];
  {
    const unsigned char* qb = eFi + (size_t)((tb >> 5) * 8) * 512 + l * 8;
#pragma unroll
    for (int kc = 0; kc < 8; kc++) qf8[kc] = LD8(qb, kc);
  }

  const f32x16 Z = {0.f, 0.f, 0.f, 0.f, 0.f, 0.f, 0.f, 0.f,
                    0.f, 0.f, 0.f, 0.f, 0.f, 0.f, 0.f, 0.f};
  const f32x16 CM6 = {-6.f, -6.f, -6.f, -6.f, -6.f, -6.f, -6.f, -6.f,
                      -6.f, -6.f, -6.f, -6.f, -6.f, -6.f, -6.f, -6.f};
  f32x16 o[5];   // o[0..3]=O^T d-blocks, o[4]=g-block (row0=L')
#pragma unroll
  for (int n2 = 0; n2 < 5; n2++) o[n2] = Z;

  // stage phase-1 tile t into buffer b: wave w does K units 4w..4w+3 (8 total)
  // and V units w+2u, u=0..4 (10 total).
  auto stageP1 = [&](int t, int b) {
#pragma unroll
    for (int q = 0; q < 4; q++)
      stage1k(eFj + (size_t)(8 * t + 4 * w + q) * 1024, kt + b * 8192 + (4 * w + q) * 1024, l);
#pragma unroll
    for (int u = 0; u < 5; u++) {
      int vu = w + 2 * u;
      int n2v = vu >> 1, uh = vu & 1;
      stage1k(eTj + (size_t)(n2v * 32 + t * 2 + uh) * 1024, vt + b * 10240 + vu * 1024, l);
    }
  };
  // stage phase-2 tile t into buffer b: K units 4w..4w+3; g unit w (2 total).
  auto stageP2 = [&](int t, int b) {
#pragma unroll
    for (int q = 0; q < 4; q++)
      stage1k(eFi + (size_t)(8 * t + 4 * w + q) * 1024, kt + b * 8192 + (4 * w + q) * 1024, l);
    stage1k(eTi + (size_t)(128 + t * 2 + w) * 1024, gt + b * 2048 + w * 1024, l);
  };

  // ---------------- phase 1: s-tile 64, 16 iterations ----------------
  stageP1(0, 0);
  __syncthreads();

  for (int st = 0; st < 16; st++) {
    const int cur = st & 1, nxt = cur ^ 1;
    if (st < 15) stageP1(st + 1, nxt);
    __builtin_amdgcn_sched_barrier(0);

    const unsigned char* kb = kt + cur * 8192 + l * 8;
    const unsigned char* vb = vt + cur * 10240 + l * 8;

    // QK: two independent 8-deep chains (C-init = -6 bias)
    __builtin_amdgcn_s_setprio(1);
    f32x16 ca0 = MFMA8(LD8(kb, 0), qf8[0], CM6);
    f32x16 ca1 = MFMA8(LD8(kb, 8), qf8[0], CM6);
#pragma unroll
    for (int dc = 1; dc < 8; dc++) {
      ca0 = MFMA8(LD8(kb, dc), qf8[dc], ca0);
      ca1 = MFMA8(LD8(kb, 8 + dc), qf8[dc], ca1);
    }
    __builtin_amdgcn_s_setprio(0);
    unsigned m0[4], m1[4];
#pragma unroll
    for (int k2 = 0; k2 < 4; k2++) {
      m0[k2] = pk4(EXPC(ca0[4 * k2]), EXPC(ca0[4 * k2 + 1]),
                   EXPC(ca0[4 * k2 + 2]), EXPC(ca0[4 * k2 + 3]));
      m1[k2] = pk4(EXPC(ca1[4 * k2]), EXPC(ca1[4 * k2 + 1]),
                   EXPC(ca1[4 * k2 + 2]), EXPC(ca1[4 * k2 + 3]));
    }
    long long pB[4];
    c2b8(m0, lh, &pB[0], &pB[1]);
    c2b8(m1, lh, &pB[2], &pB[3]);
    __builtin_amdgcn_s_setprio(1);
#pragma unroll
    for (int n2 = 0; n2 < 5; n2++)
#pragma unroll
      for (int sc = 0; sc < 4; sc++)
        o[n2] = MFMA8(LD8(vb, n2 * 4 + sc), pB[sc], o[n2]);
    __builtin_amdgcn_s_setprio(0);
    __syncthreads();
  }

  // stage phase-2 tile 0 (gt overlays vt -- all reads of vt are behind the
  // final syncthreads above)
  stageP2(0, 0);

  // ---- interphase: nn^T = O^T / L'; fp8 B-frags via shfl ----
  float Lme = o[4][0];
  float Lo = __shfl_xor(Lme, 32, 64);
  float inv = 1.0f / (lh ? Lo : Lme);
  long long qf2[8];
#pragma unroll
  for (int n2 = 0; n2 < 4; n2++) {
    unsigned mm[4];
#pragma unroll
    for (int k2 = 0; k2 < 4; k2++)
      mm[k2] = pk4(o[n2][4 * k2] * inv, o[n2][4 * k2 + 1] * inv,
                   o[n2][4 * k2 + 2] * inv, o[n2][4 * k2 + 3] * inv);
    c2b8(mm, lh, &qf2[2 * n2], &qf2[2 * n2 + 1]);
  }
  f32x16 acc6 = Z;
  __syncthreads();

  // ---------------- phase 2: s-tile 64, 16 iterations, K + g-block ----------------
  for (int st = 0; st < 16; st++) {
    const int cur = st & 1, nxt = cur ^ 1;
    if (st < 15) stageP2(st + 1, nxt);
    __builtin_amdgcn_sched_barrier(0);

    const unsigned char* kb = kt + cur * 8192 + l * 8;
    const unsigned char* gb = gt + cur * 2048 + l * 8;

    __builtin_amdgcn_s_setprio(1);
    f32x16 ca0 = MFMA8(LD8(kb, 0), qf2[0], CM6);
    f32x16 ca1 = MFMA8(LD8(kb, 8), qf2[0], CM6);
#pragma unroll
    for (int dc = 1; dc < 8; dc++) {
      ca0 = MFMA8(LD8(kb, dc), qf2[dc], ca0);
      ca1 = MFMA8(LD8(kb, 8 + dc), qf2[dc], ca1);
    }
    __builtin_amdgcn_s_setprio(0);
    unsigned m0[4], m1[4];
#pragma unroll
    for (int k2 = 0; k2 < 4; k2++) {
      m0[k2] = pk4(EXPC(ca0[4 * k2]), EXPC(ca0[4 * k2 + 1]),
                   EXPC(ca0[4 * k2 + 2]), EXPC(ca0[4 * k2 + 3]));
      m1[k2] = pk4(EXPC(ca1[4 * k2]), EXPC(ca1[4 * k2 + 1]),
                   EXPC(ca1[4 * k2 + 2]), EXPC(ca1[4 * k2 + 3]));
    }
    long long pB[4];
    c2b8(m0, lh, &pB[0], &pB[1]);
    c2b8(m1, lh, &pB[2], &pB[3]);
    __builtin_amdgcn_s_setprio(1);
#pragma unroll
    for (int sc = 0; sc < 4; sc++)
      acc6 = MFMA8(LD8(gb, sc), pB[sc], acc6);
    __builtin_amdgcn_s_setprio(0);
    __syncthreads();
  }

  // ---- epilogue: pred = tp/L2 (rows 0,1 at lh=0), MSE, fused finalize ----
  float local = 0.f;
  if (lh == 0) {
    float pred = acc6[1] / acc6[0];
    float tt = steps[i * T_ + tb + l31];
    float dd = pred - tt;
    local = dd * dd;
  }
  local = waveSum(local);
  if (l == 0) blred[w] = local;
  __syncthreads();
  if (tid == 0) {
    atomicAdd(loss_acc, blred[0] + blred[1]);
    __threadfence();
    unsigned old = atomicAdd(cnt, 1u);
    if (old == (unsigned)(gridDim.x - 1)) {
      float v = atomicAdd(loss_acc, 0.0f);
      out[0] = v * (1.0f / (float)(NPAIR * T_));
    }
  }
}

extern "C" void kernel_launch(void* const* d_in, const int* in_sizes, int n_in,
                              void* d_out, int out_size, void* d_ws, size_t ws_size,
                              hipStream_t stream) {
  const float* embs = (const float*)d_in[0];
  const int* frame_idxs = (const int*)d_in[1];
  const int* video_len = (const int*)d_in[2];
  float* out = (float*)d_out;

  char* ws = (char*)d_ws;
  float* acc = (float*)ws;                                  // @0
  unsigned* cnt = (unsigned*)(ws + 512);                    // @512
  float* steps = (float*)(ws + 4096);                       // 8192 f32
  unsigned char* e8F = (unsigned char*)(ws + 65536);        // 1 MB
  unsigned char* e8T = e8F + (size_t)8 * B8F;               // 1.25 MB

  convert_kernel<<<dim3(256), dim3(256), 0, stream>>>(embs, frame_idxs, video_len,
                                                      e8F, e8T, steps, acc, cnt);
  tcc_main<<<dim3(NPAIR * 16), dim3(128), 0, stream>>>(e8F, e8T, steps, acc, cnt, out);
}